// Round 2
// baseline (445.647 us; speedup 1.0000x reference)
//
#include <hip/hip_runtime.h>
#include <hip/hip_bf16.h>
#include <stdint.h>

#define B_ 2
#define T_ 2048
#define C_ 2048
#define NH_ 16
#define NKVH_ 4
#define HS_ 128
#define QKV_ 3072
#define NTOK_ 4096

typedef __attribute__((ext_vector_type(4))) float f32x4;
typedef __attribute__((ext_vector_type(8))) short s16x8;

__device__ __forceinline__ short f2bf(float f) {
    union { float f; unsigned u; } v; v.f = f;
    unsigned r = v.u + 0x7FFFu + ((v.u >> 16) & 1u);
    return (short)(r >> 16);
}

__device__ __forceinline__ void async16(const void* g, void* l) {
    __builtin_amdgcn_global_load_lds(
        (const __attribute__((address_space(1))) void*)g,
        (__attribute__((address_space(3))) void*)l, 16, 0, 0);
}

// ---------------- cast x -> bf16 ----------------
__global__ void cast_bf16_kernel(const float* __restrict__ x, short* __restrict__ out, int n8) {
    int i = blockIdx.x * 256 + threadIdx.x;
    if (i >= n8) return;
    const float4* p = (const float4*)x + (size_t)i * 2;
    float4 a = p[0], b = p[1];
    short o[8] = { f2bf(a.x), f2bf(a.y), f2bf(a.z), f2bf(a.w),
                   f2bf(b.x), f2bf(b.y), f2bf(b.z), f2bf(b.w) };
    *(int4*)(out + (size_t)i * 8) = *(const int4*)o;
}

// ---------------- W [K][N] f32 -> WT [N][K] bf16 ----------------
__global__ void transcast(const float* __restrict__ W, short* __restrict__ WT, int Kd, int Nd) {
    __shared__ float tile[64][65];
    int k0 = blockIdx.x * 64, n0 = blockIdx.y * 64;
    int tid = threadIdx.x;
    int cl = tid & 63, rw = tid >> 6;
    for (int it = 0; it < 16; ++it) {
        int r = it * 4 + rw;
        tile[r][cl] = W[(size_t)(k0 + r) * Nd + n0 + cl];
    }
    __syncthreads();
    for (int it = 0; it < 16; ++it) {
        int n = it * 4 + rw;
        WT[(size_t)(n0 + n) * Kd + k0 + cl] = f2bf(tile[cl][n]);
    }
}

// ---------------- GEMM: A[M][K] bf16 x Bt[N][K] bf16 -> C[M][N] f32 + bias ----------------
__global__ __launch_bounds__(256, 2) void gemm_bt(
    const short* __restrict__ A, const short* __restrict__ Bt,
    const float* __restrict__ bias, float* __restrict__ Cc,
    int M, int N, int K)
{
    __shared__ short As[128 * 64];
    __shared__ short Bs[128 * 64];
    int tid = threadIdx.x;
    int w = tid >> 6, l = tid & 63;
    int lr = l & 15, lg = l >> 4;
    int bm = blockIdx.x, bn = blockIdx.y;
    int wm = (w >> 1) * 64, wn = (w & 1) * 64;
    f32x4 acc[4][4];
#pragma unroll
    for (int i = 0; i < 4; i++)
#pragma unroll
        for (int j = 0; j < 4; j++) { acc[i][j][0]=0.f; acc[i][j][1]=0.f; acc[i][j][2]=0.f; acc[i][j][3]=0.f; }
    int arow = l >> 3, acol = (l & 7) * 8;
    for (int k0 = 0; k0 < K; k0 += 64) {
#pragma unroll
        for (int i = 0; i < 4; i++) {
            int chunk = w * 4 + i;
            int row = chunk * 8 + arow;
            async16(A  + (size_t)(bm * 128 + row) * K + k0 + acol, (char*)As + chunk * 1024);
            async16(Bt + (size_t)(bn * 128 + row) * K + k0 + acol, (char*)Bs + chunk * 1024);
        }
        __syncthreads();
#pragma unroll
        for (int ks = 0; ks < 2; ks++) {
            s16x8 af[4], bf[4];
#pragma unroll
            for (int mi = 0; mi < 4; mi++)
                af[mi] = *(const s16x8*)&As[(wm + mi * 16 + lr) * 64 + ks * 32 + lg * 8];
#pragma unroll
            for (int ni = 0; ni < 4; ni++)
                bf[ni] = *(const s16x8*)&Bs[(wn + ni * 16 + lr) * 64 + ks * 32 + lg * 8];
#pragma unroll
            for (int mi = 0; mi < 4; mi++)
#pragma unroll
                for (int ni = 0; ni < 4; ni++)
                    acc[mi][ni] = __builtin_amdgcn_mfma_f32_16x16x32_bf16(af[mi], bf[ni], acc[mi][ni], 0, 0, 0);
        }
        __syncthreads();
    }
#pragma unroll
    for (int mi = 0; mi < 4; mi++) {
        int row = bm * 128 + wm + mi * 16 + lg * 4;
#pragma unroll
        for (int ni = 0; ni < 4; ni++) {
            int col = bn * 128 + wn + ni * 16 + lr;
            float bv = bias[col];
#pragma unroll
            for (int j = 0; j < 4; j++)
                Cc[(size_t)(row + j) * N + col] = acc[mi][ni][j] + bv;
        }
    }
}

// ---------------- RoPE + scatter to Q [B][NH][T][HS], K [B][G][T][HS] bf16 ----------------
__global__ void rope_scatter(const float* __restrict__ qkv,
                             const float* __restrict__ fcos, const float* __restrict__ fsin,
                             short* __restrict__ Q, short* __restrict__ Kb)
{
    int idx = blockIdx.x * 256 + threadIdx.x;
    int tok = idx / 1280, p = idx - tok * 1280;
    if (tok >= NTOK_) return;
    int b = tok >> 11, t = tok & 2047;
    if (p < 1024) {
        int h = p >> 6, i = p & 63;
        const float* src = qkv + (size_t)tok * QKV_ + h * 128 + 2 * i;
        float re = src[0], im = src[1];
        float c = fcos[t * 64 + i], s = fsin[t * 64 + i];
        unsigned lo = (unsigned short)f2bf(re * c - im * s);
        unsigned hi = (unsigned short)f2bf(re * s + im * c);
        *(unsigned*)(Q + ((size_t)(b * NH_ + h) * T_ + t) * HS_ + 2 * i) = lo | (hi << 16);
    } else {
        int pk = p - 1024; int g = pk >> 6, i = pk & 63;
        const float* src = qkv + (size_t)tok * QKV_ + C_ + g * 128 + 2 * i;
        float re = src[0], im = src[1];
        float c = fcos[t * 64 + i], s = fsin[t * 64 + i];
        unsigned lo = (unsigned short)f2bf(re * c - im * s);
        unsigned hi = (unsigned short)f2bf(re * s + im * c);
        *(unsigned*)(Kb + ((size_t)(b * NKVH_ + g) * T_ + t) * HS_ + 2 * i) = lo | (hi << 16);
    }
}

// ---------------- V part of qkv -> VT [B][G][HS][T] bf16 ----------------
__global__ void v_transpose(const float* __restrict__ qkv, short* __restrict__ VT) {
    __shared__ float tile[64][65];
    int t0 = blockIdx.x * 64, d0 = blockIdx.y * 64;
    int bg = blockIdx.z; int b = bg >> 2, g = bg & 3;
    int tid = threadIdx.x; int cl = tid & 63, rw = tid >> 6;
    const float* base = qkv + (size_t)(b * T_ + t0) * QKV_ + C_ + NKVH_ * HS_ + g * HS_ + d0;
    for (int it = 0; it < 16; ++it) {
        int r = it * 4 + rw;
        tile[r][cl] = base[(size_t)r * QKV_ + cl];
    }
    __syncthreads();
    short* out = VT + ((size_t)(b * NKVH_ + g) * HS_ + d0) * T_ + t0;
    for (int it = 0; it < 16; ++it) {
        int d = it * 4 + rw;
        out[(size_t)d * T_ + cl] = f2bf(tile[cl][d]);
    }
}

// ---------------- Flash attention, causal GQA ----------------
// grid: (B*NH, T/64 q-tiles). block: 256 (4 waves x 16 q-rows).
// LPT: qt reversed so the longest blocks (qt=31) dispatch first.
// launch_bounds(256,4): 4 blocks/CU co-resident (40KB LDS x4 = 160KB exactly).
__global__ __launch_bounds__(256, 4) void attn_kernel(
    const short* __restrict__ Qg, const short* __restrict__ Kg,
    const short* __restrict__ VTg, short* __restrict__ Y)
{
    __shared__ short Ks[64 * 128];   // [s][d], swizzled, 256B rows
    __shared__ short VTs[128 * 64];  // [d][s], swizzled, 128B rows
    __shared__ short Ps[4][16 * 64]; // per-wave P, swizzled, 128B rows
    int tid = threadIdx.x, w = tid >> 6, l = tid & 63;
    int lr = l & 15, lg = l >> 4;
    int qt = 31 - (int)blockIdx.y;   // LPT: longest first
    int bh = blockIdx.x;
    int b = bh >> 4, h = bh & 15, g = h >> 2;
    const short* Qb = Qg + (size_t)(b * NH_ + h) * T_ * HS_;
    const short* Kb = Kg + (size_t)(b * NKVH_ + g) * T_ * HS_;
    const short* Vb = VTg + (size_t)(b * NKVH_ + g) * HS_ * T_;

    s16x8 qf[4];
    int qrow = qt * 64 + w * 16 + lr;
#pragma unroll
    for (int kc = 0; kc < 4; kc++)
        qf[kc] = *(const s16x8*)(Qb + (size_t)qrow * HS_ + kc * 32 + lg * 8);

    f32x4 oacc[8];
#pragma unroll
    for (int i = 0; i < 8; i++) { oacc[i][0]=0.f; oacc[i][1]=0.f; oacc[i][2]=0.f; oacc[i][3]=0.f; }
    float m[4] = {-1e30f, -1e30f, -1e30f, -1e30f};
    float lsum[4] = {0.f, 0.f, 0.f, 0.f};
    const float scale = 0.08838834764831845f; // 1/sqrt(128)
    int qg0 = qt * 64 + w * 16 + lg * 4;

    for (int st = 0; st <= qt; ++st) {
        // stage K (pre-swizzled source -> linear LDS dest; reads use same XOR)
#pragma unroll
        for (int i = 0; i < 4; i++) {
            int chunk = w * 4 + i;
            int poff = chunk * 1024 + l * 16;
            int qoffk = poff ^ (((poff >> 8) & 7) << 4);
            async16(Kb + (size_t)(st * 64 + (qoffk >> 8)) * HS_ + ((qoffk & 255) >> 1),
                    (char*)Ks + chunk * 1024);
            int qoffv = poff ^ (((poff >> 7) & 7) << 4);
            async16(Vb + (size_t)(qoffv >> 7) * T_ + st * 64 + ((qoffv & 127) >> 1),
                    (char*)VTs + chunk * 1024);
        }
        __syncthreads();

        // S = Q K^T
        f32x4 sv[4];
#pragma unroll
        for (int ni = 0; ni < 4; ni++) {
            f32x4 a; a[0]=0.f; a[1]=0.f; a[2]=0.f; a[3]=0.f;
#pragma unroll
            for (int kc = 0; kc < 4; kc++) {
                int lo = ((ni * 16 + lr) << 8) + ((kc * 32 + lg * 8) << 1);
                int po = lo ^ (((lo >> 8) & 7) << 4);
                s16x8 kf = *(const s16x8*)((const char*)Ks + po);
                a = __builtin_amdgcn_mfma_f32_16x16x32_bf16(qf[kc], kf, a, 0, 0, 0);
            }
            sv[ni] = a;
        }
        // scale + causal mask + row max
        float tmax[4] = {-1e30f, -1e30f, -1e30f, -1e30f};
#pragma unroll
        for (int ni = 0; ni < 4; ni++) {
            int sg = st * 64 + ni * 16 + lr;
#pragma unroll
            for (int j = 0; j < 4; j++) {
                float s = sv[ni][j] * scale;
                if (sg > qg0 + j) s = -1e30f;
                sv[ni][j] = s;
                tmax[j] = fmaxf(tmax[j], s);
            }
        }
#pragma unroll
        for (int msk = 1; msk < 16; msk <<= 1)
#pragma unroll
            for (int j = 0; j < 4; j++)
                tmax[j] = fmaxf(tmax[j], __shfl_xor(tmax[j], msk));
        float corr[4];
#pragma unroll
        for (int j = 0; j < 4; j++) {
            float mn = fmaxf(m[j], tmax[j]);
            corr[j] = __expf(m[j] - mn);
            m[j] = mn;
        }
        float rsum[4] = {0.f, 0.f, 0.f, 0.f};
#pragma unroll
        for (int ni = 0; ni < 4; ni++)
#pragma unroll
            for (int j = 0; j < 4; j++) {
                float p = __expf(sv[ni][j] - m[j]);
                sv[ni][j] = p;
                rsum[j] += p;
            }
#pragma unroll
        for (int msk = 1; msk < 16; msk <<= 1)
#pragma unroll
            for (int j = 0; j < 4; j++)
                rsum[j] += __shfl_xor(rsum[j], msk);
#pragma unroll
        for (int j = 0; j < 4; j++)
            lsum[j] = lsum[j] * corr[j] + rsum[j];
#pragma unroll
        for (int dn = 0; dn < 8; dn++)
#pragma unroll
            for (int j = 0; j < 4; j++)
                oacc[dn][j] *= corr[j];
        // P -> wave-private LDS (C-layout -> A-layout bounce), swizzled
#pragma unroll
        for (int ni = 0; ni < 4; ni++)
#pragma unroll
            for (int j = 0; j < 4; j++) {
                int lo = (lg * 4 + j) * 128 + (ni * 16 + lr) * 2;
                int po = lo ^ (((lo >> 7) & 7) << 4);
                *(short*)((char*)&Ps[w][0] + po) = f2bf(sv[ni][j]);
            }
        // O += P V
#pragma unroll
        for (int sc = 0; sc < 2; sc++) {
            int lo = lr * 128 + sc * 64 + lg * 16;
            int po = lo ^ (((lo >> 7) & 7) << 4);
            s16x8 pf = *(const s16x8*)((const char*)&Ps[w][0] + po);
#pragma unroll
            for (int dn = 0; dn < 8; dn++) {
                int lov = (dn * 16 + lr) * 128 + (sc * 32 + lg * 8) * 2;
                int pov = lov ^ (((lov >> 7) & 7) << 4);
                s16x8 vf = *(const s16x8*)((const char*)VTs + pov);
                oacc[dn] = __builtin_amdgcn_mfma_f32_16x16x32_bf16(pf, vf, oacc[dn], 0, 0, 0);
            }
        }
        __syncthreads();
    }

    float inv[4];
#pragma unroll
    for (int j = 0; j < 4; j++) inv[j] = 1.0f / lsum[j];
#pragma unroll
    for (int dn = 0; dn < 8; dn++)
#pragma unroll
        for (int j = 0; j < 4; j++) {
            int trow = qt * 64 + w * 16 + lg * 4 + j;
            Y[(size_t)(b * T_ + trow) * C_ + h * 128 + dn * 16 + lr] = f2bf(oacc[dn][j] * inv[j]);
        }
}

extern "C" void kernel_launch(void* const* d_in, const int* in_sizes, int n_in,
                              void* d_out, int out_size, void* d_ws, size_t ws_size,
                              hipStream_t stream)
{
    const float* x      = (const float*)d_in[0];
    const float* fcos   = (const float*)d_in[1];
    const float* fsin   = (const float*)d_in[2];
    const float* W_attn = (const float*)d_in[3];
    const float* b_attn = (const float*)d_in[4];
    const float* W_proj = (const float*)d_in[5];
    const float* b_proj = (const float*)d_in[6];
    float* out = (float*)d_out;
    char* ws = (char*)d_ws;

    // workspace layout (92.3 MB, with dead-buffer aliasing)
    short* xb  = (short*)(ws + 0);          // 16,777,216
    float* qkv = (float*)(ws + 16777216);   // 50,331,648  [16777216 .. 67108864)
    short* y   = (short*)(ws + 16777216);   // alias qkv lower (qkv dead by then)
    short* WpT = (short*)(ws + 33554432);   // alias qkv upper, 8,388,608
    short* WaT = (short*)(ws + 67108864);   // 12,582,912
    short* Qb  = (short*)(ws + 67108864);   // alias WaT (dead after gemm1), 16,777,216
    short* Kb  = (short*)(ws + 83886080);   // 4,194,304
    short* VT  = (short*)(ws + 88080384);   // 4,194,304

    cast_bf16_kernel<<<4096, 256, 0, stream>>>(x, xb, NTOK_ * C_ / 8);
    transcast<<<dim3(32, 48), 256, 0, stream>>>(W_attn, WaT, C_, QKV_);
    gemm_bt<<<dim3(32, 24), 256, 0, stream>>>(xb, WaT, b_attn, qkv, NTOK_, QKV_, C_);
    rope_scatter<<<20480, 256, 0, stream>>>(qkv, fcos, fsin, Qb, Kb);
    v_transpose<<<dim3(32, 2, 8), 256, 0, stream>>>(qkv, VT);
    transcast<<<dim3(32, 32), 256, 0, stream>>>(W_proj, WpT, C_, C_);
    attn_kernel<<<dim3(32, 32), 256, 0, stream>>>(Qb, Kb, VT, y);
    gemm_bt<<<dim3(32, 16), 256, 0, stream>>>(y, WpT, b_proj, out, NTOK_, C_, C_);
}

// Round 4
// 244.419 us; speedup vs baseline: 1.8233x; 1.8233x over previous
//
#include <hip/hip_runtime.h>
#include <hip/hip_bf16.h>
#include <stdint.h>

#define B_ 2
#define T_ 2048
#define C_ 2048
#define NH_ 16
#define NKVH_ 4
#define HS_ 128
#define QKV_ 3072
#define NTOK_ 4096

typedef __attribute__((ext_vector_type(4))) float f32x4;
typedef __attribute__((ext_vector_type(8))) short s16x8;

__device__ __forceinline__ short f2bf(float f) {
    union { float f; unsigned u; } v; v.f = f;
    unsigned r = v.u + 0x7FFFu + ((v.u >> 16) & 1u);
    return (short)(r >> 16);
}

__device__ __forceinline__ void async16(const void* g, void* l) {
    __builtin_amdgcn_global_load_lds(
        (const __attribute__((address_space(1))) void*)g,
        (__attribute__((address_space(3))) void*)l, 16, 0, 0);
}

// ---------------- cast x -> bf16 ----------------
__global__ void cast_bf16_kernel(const float* __restrict__ x, short* __restrict__ out, int n8) {
    int i = blockIdx.x * 256 + threadIdx.x;
    if (i >= n8) return;
    const float4* p = (const float4*)x + (size_t)i * 2;
    float4 a = p[0], b = p[1];
    short o[8] = { f2bf(a.x), f2bf(a.y), f2bf(a.z), f2bf(a.w),
                   f2bf(b.x), f2bf(b.y), f2bf(b.z), f2bf(b.w) };
    *(int4*)(out + (size_t)i * 8) = *(const int4*)o;
}

// ---------------- W [K][N] f32 -> WT [N][K] bf16 ----------------
__global__ void transcast(const float* __restrict__ W, short* __restrict__ WT, int Kd, int Nd) {
    __shared__ float tile[64][65];
    int k0 = blockIdx.x * 64, n0 = blockIdx.y * 64;
    int tid = threadIdx.x;
    int cl = tid & 63, rw = tid >> 6;
    for (int it = 0; it < 16; ++it) {
        int r = it * 4 + rw;
        tile[r][cl] = W[(size_t)(k0 + r) * Nd + n0 + cl];
    }
    __syncthreads();
    for (int it = 0; it < 16; ++it) {
        int n = it * 4 + rw;
        WT[(size_t)(n0 + n) * Kd + k0 + cl] = f2bf(tile[cl][n]);
    }
}

// ---------------- GEMM: A[M][K] bf16 x Bt[N][K] bf16 -> C[M][N] f32 + bias ----------------
__global__ __launch_bounds__(256, 2) void gemm_bt(
    const short* __restrict__ A, const short* __restrict__ Bt,
    const float* __restrict__ bias, float* __restrict__ Cc,
    int M, int N, int K)
{
    __shared__ short As[128 * 64];
    __shared__ short Bs[128 * 64];
    int tid = threadIdx.x;
    int w = tid >> 6, l = tid & 63;
    int lr = l & 15, lg = l >> 4;
    int bm = blockIdx.x, bn = blockIdx.y;
    int wm = (w >> 1) * 64, wn = (w & 1) * 64;
    f32x4 acc[4][4];
#pragma unroll
    for (int i = 0; i < 4; i++)
#pragma unroll
        for (int j = 0; j < 4; j++) { acc[i][j][0]=0.f; acc[i][j][1]=0.f; acc[i][j][2]=0.f; acc[i][j][3]=0.f; }
    int arow = l >> 3, acol = (l & 7) * 8;
    for (int k0 = 0; k0 < K; k0 += 64) {
#pragma unroll
        for (int i = 0; i < 4; i++) {
            int chunk = w * 4 + i;
            int row = chunk * 8 + arow;
            async16(A  + (size_t)(bm * 128 + row) * K + k0 + acol, (char*)As + chunk * 1024);
            async16(Bt + (size_t)(bn * 128 + row) * K + k0 + acol, (char*)Bs + chunk * 1024);
        }
        __syncthreads();
#pragma unroll
        for (int ks = 0; ks < 2; ks++) {
            s16x8 af[4], bf[4];
#pragma unroll
            for (int mi = 0; mi < 4; mi++)
                af[mi] = *(const s16x8*)&As[(wm + mi * 16 + lr) * 64 + ks * 32 + lg * 8];
#pragma unroll
            for (int ni = 0; ni < 4; ni++)
                bf[ni] = *(const s16x8*)&Bs[(wn + ni * 16 + lr) * 64 + ks * 32 + lg * 8];
#pragma unroll
            for (int mi = 0; mi < 4; mi++)
#pragma unroll
                for (int ni = 0; ni < 4; ni++)
                    acc[mi][ni] = __builtin_amdgcn_mfma_f32_16x16x32_bf16(af[mi], bf[ni], acc[mi][ni], 0, 0, 0);
        }
        __syncthreads();
    }
#pragma unroll
    for (int mi = 0; mi < 4; mi++) {
        int row = bm * 128 + wm + mi * 16 + lg * 4;
#pragma unroll
        for (int ni = 0; ni < 4; ni++) {
            int col = bn * 128 + wn + ni * 16 + lr;
            float bv = bias[col];
#pragma unroll
            for (int j = 0; j < 4; j++)
                Cc[(size_t)(row + j) * N + col] = acc[mi][ni][j] + bv;
        }
    }
}

// ---------------- RoPE + scatter to Q [B][NH][T][HS], K [B][G][T][HS] bf16 ----------------
__global__ void rope_scatter(const float* __restrict__ qkv,
                             const float* __restrict__ fcos, const float* __restrict__ fsin,
                             short* __restrict__ Q, short* __restrict__ Kb)
{
    int idx = blockIdx.x * 256 + threadIdx.x;
    int tok = idx / 1280, p = idx - tok * 1280;
    if (tok >= NTOK_) return;
    int b = tok >> 11, t = tok & 2047;
    if (p < 1024) {
        int h = p >> 6, i = p & 63;
        const float* src = qkv + (size_t)tok * QKV_ + h * 128 + 2 * i;
        float re = src[0], im = src[1];
        float c = fcos[t * 64 + i], s = fsin[t * 64 + i];
        unsigned lo = (unsigned short)f2bf(re * c - im * s);
        unsigned hi = (unsigned short)f2bf(re * s + im * c);
        *(unsigned*)(Q + ((size_t)(b * NH_ + h) * T_ + t) * HS_ + 2 * i) = lo | (hi << 16);
    } else {
        int pk = p - 1024; int g = pk >> 6, i = pk & 63;
        const float* src = qkv + (size_t)tok * QKV_ + C_ + g * 128 + 2 * i;
        float re = src[0], im = src[1];
        float c = fcos[t * 64 + i], s = fsin[t * 64 + i];
        unsigned lo = (unsigned short)f2bf(re * c - im * s);
        unsigned hi = (unsigned short)f2bf(re * s + im * c);
        *(unsigned*)(Kb + ((size_t)(b * NKVH_ + g) * T_ + t) * HS_ + 2 * i) = lo | (hi << 16);
    }
}

// ---------------- V part of qkv -> VT [B][G][HS][T] bf16 ----------------
__global__ void v_transpose(const float* __restrict__ qkv, short* __restrict__ VT) {
    __shared__ float tile[64][65];
    int t0 = blockIdx.x * 64, d0 = blockIdx.y * 64;
    int bg = blockIdx.z; int b = bg >> 2, g = bg & 3;
    int tid = threadIdx.x; int cl = tid & 63, rw = tid >> 6;
    const float* base = qkv + (size_t)(b * T_ + t0) * QKV_ + C_ + NKVH_ * HS_ + g * HS_ + d0;
    for (int it = 0; it < 16; ++it) {
        int r = it * 4 + rw;
        tile[r][cl] = base[(size_t)r * QKV_ + cl];
    }
    __syncthreads();
    short* out = VT + ((size_t)(b * NKVH_ + g) * HS_ + d0) * T_ + t0;
    for (int it = 0; it < 16; ++it) {
        int d = it * 4 + rw;
        out[(size_t)d * T_ + cl] = f2bf(tile[cl][d]);
    }
}

// ---------------- Flash attention, causal GQA ----------------
// grid: (B*NH=32 fast, T/64=32 q-tiles slow). block: 256 (4 waves x 16 q-rows).
// LPT: qt reversed so the longest blocks (qt=31) dispatch first.
// launch_bounds(256,2): DO NOT raise — (256,4) forces <=128 unified regs -> spills
// (round 2: VGPR 124->64, FETCH_SIZE 37MB->224MB, dur 174->307us).
// grid.x MUST be 32 (b=bh>>4 assumes B*NH=32; 64 corrupted WpT via OOB Y writes, round 3).
__global__ __launch_bounds__(256, 2) void attn_kernel(
    const short* __restrict__ Qg, const short* __restrict__ Kg,
    const short* __restrict__ VTg, short* __restrict__ Y)
{
    __shared__ short Ks[64 * 128];   // [s][d], swizzled, 256B rows
    __shared__ short VTs[128 * 64];  // [d][s], swizzled, 128B rows
    __shared__ short Ps[4][16 * 64]; // per-wave P, swizzled, 128B rows
    int tid = threadIdx.x, w = tid >> 6, l = tid & 63;
    int lr = l & 15, lg = l >> 4;
    int qt = 31 - (int)blockIdx.y;   // LPT: longest first
    int bh = blockIdx.x;
    int b = bh >> 4, h = bh & 15, g = h >> 2;
    const short* Qb = Qg + (size_t)(b * NH_ + h) * T_ * HS_;
    const short* Kb = Kg + (size_t)(b * NKVH_ + g) * T_ * HS_;
    const short* Vb = VTg + (size_t)(b * NKVH_ + g) * HS_ * T_;

    s16x8 qf[4];
    int qrow = qt * 64 + w * 16 + lr;
#pragma unroll
    for (int kc = 0; kc < 4; kc++)
        qf[kc] = *(const s16x8*)(Qb + (size_t)qrow * HS_ + kc * 32 + lg * 8);

    f32x4 oacc[8];
#pragma unroll
    for (int i = 0; i < 8; i++) { oacc[i][0]=0.f; oacc[i][1]=0.f; oacc[i][2]=0.f; oacc[i][3]=0.f; }
    float m[4] = {-1e30f, -1e30f, -1e30f, -1e30f};
    float lsum[4] = {0.f, 0.f, 0.f, 0.f};
    const float scale = 0.08838834764831845f; // 1/sqrt(128)
    int qg0 = qt * 64 + w * 16 + lg * 4;

    for (int st = 0; st <= qt; ++st) {
        // stage K (pre-swizzled source -> linear LDS dest; reads use same XOR)
#pragma unroll
        for (int i = 0; i < 4; i++) {
            int chunk = w * 4 + i;
            int poff = chunk * 1024 + l * 16;
            int qoffk = poff ^ (((poff >> 8) & 7) << 4);
            async16(Kb + (size_t)(st * 64 + (qoffk >> 8)) * HS_ + ((qoffk & 255) >> 1),
                    (char*)Ks + chunk * 1024);
            int qoffv = poff ^ (((poff >> 7) & 7) << 4);
            async16(Vb + (size_t)(qoffv >> 7) * T_ + st * 64 + ((qoffv & 127) >> 1),
                    (char*)VTs + chunk * 1024);
        }
        __syncthreads();

        // S = Q K^T
        f32x4 sv[4];
#pragma unroll
        for (int ni = 0; ni < 4; ni++) {
            f32x4 a; a[0]=0.f; a[1]=0.f; a[2]=0.f; a[3]=0.f;
#pragma unroll
            for (int kc = 0; kc < 4; kc++) {
                int lo = ((ni * 16 + lr) << 8) + ((kc * 32 + lg * 8) << 1);
                int po = lo ^ (((lo >> 8) & 7) << 4);
                s16x8 kf = *(const s16x8*)((const char*)Ks + po);
                a = __builtin_amdgcn_mfma_f32_16x16x32_bf16(qf[kc], kf, a, 0, 0, 0);
            }
            sv[ni] = a;
        }
        // scale + causal mask + row max
        float tmax[4] = {-1e30f, -1e30f, -1e30f, -1e30f};
#pragma unroll
        for (int ni = 0; ni < 4; ni++) {
            int sg = st * 64 + ni * 16 + lr;
#pragma unroll
            for (int j = 0; j < 4; j++) {
                float s = sv[ni][j] * scale;
                if (sg > qg0 + j) s = -1e30f;
                sv[ni][j] = s;
                tmax[j] = fmaxf(tmax[j], s);
            }
        }
#pragma unroll
        for (int msk = 1; msk < 16; msk <<= 1)
#pragma unroll
            for (int j = 0; j < 4; j++)
                tmax[j] = fmaxf(tmax[j], __shfl_xor(tmax[j], msk));
        float corr[4];
#pragma unroll
        for (int j = 0; j < 4; j++) {
            float mn = fmaxf(m[j], tmax[j]);
            corr[j] = __expf(m[j] - mn);
            m[j] = mn;
        }
        float rsum[4] = {0.f, 0.f, 0.f, 0.f};
#pragma unroll
        for (int ni = 0; ni < 4; ni++)
#pragma unroll
            for (int j = 0; j < 4; j++) {
                float p = __expf(sv[ni][j] - m[j]);
                sv[ni][j] = p;
                rsum[j] += p;
            }
#pragma unroll
        for (int msk = 1; msk < 16; msk <<= 1)
#pragma unroll
            for (int j = 0; j < 4; j++)
                rsum[j] += __shfl_xor(rsum[j], msk);
#pragma unroll
        for (int j = 0; j < 4; j++)
            lsum[j] = lsum[j] * corr[j] + rsum[j];
#pragma unroll
        for (int dn = 0; dn < 8; dn++)
#pragma unroll
            for (int j = 0; j < 4; j++)
                oacc[dn][j] *= corr[j];
        // P -> wave-private LDS (C-layout -> A-layout bounce), swizzled
#pragma unroll
        for (int ni = 0; ni < 4; ni++)
#pragma unroll
            for (int j = 0; j < 4; j++) {
                int lo = (lg * 4 + j) * 128 + (ni * 16 + lr) * 2;
                int po = lo ^ (((lo >> 7) & 7) << 4);
                *(short*)((char*)&Ps[w][0] + po) = f2bf(sv[ni][j]);
            }
        // O += P V
#pragma unroll
        for (int sc = 0; sc < 2; sc++) {
            int lo = lr * 128 + sc * 64 + lg * 16;
            int po = lo ^ (((lo >> 7) & 7) << 4);
            s16x8 pf = *(const s16x8*)((const char*)&Ps[w][0] + po);
#pragma unroll
            for (int dn = 0; dn < 8; dn++) {
                int lov = (dn * 16 + lr) * 128 + (sc * 32 + lg * 8) * 2;
                int pov = lov ^ (((lov >> 7) & 7) << 4);
                s16x8 vf = *(const s16x8*)((const char*)VTs + pov);
                oacc[dn] = __builtin_amdgcn_mfma_f32_16x16x32_bf16(pf, vf, oacc[dn], 0, 0, 0);
            }
        }
        __syncthreads();
    }

    float inv[4];
#pragma unroll
    for (int j = 0; j < 4; j++) inv[j] = 1.0f / lsum[j];
#pragma unroll
    for (int dn = 0; dn < 8; dn++)
#pragma unroll
        for (int j = 0; j < 4; j++) {
            int trow = qt * 64 + w * 16 + lg * 4 + j;
            Y[(size_t)(b * T_ + trow) * C_ + h * 128 + dn * 16 + lr] = f2bf(oacc[dn][j] * inv[j]);
        }
}

extern "C" void kernel_launch(void* const* d_in, const int* in_sizes, int n_in,
                              void* d_out, int out_size, void* d_ws, size_t ws_size,
                              hipStream_t stream)
{
    const float* x      = (const float*)d_in[0];
    const float* fcos   = (const float*)d_in[1];
    const float* fsin   = (const float*)d_in[2];
    const float* W_attn = (const float*)d_in[3];
    const float* b_attn = (const float*)d_in[4];
    const float* W_proj = (const float*)d_in[5];
    const float* b_proj = (const float*)d_in[6];
    float* out = (float*)d_out;
    char* ws = (char*)d_ws;

    // workspace layout (92.3 MB, with dead-buffer aliasing)
    short* xb  = (short*)(ws + 0);          // 16,777,216
    float* qkv = (float*)(ws + 16777216);   // 50,331,648  [16777216 .. 67108864)
    short* y   = (short*)(ws + 16777216);   // alias qkv lower (qkv dead by then)
    short* WpT = (short*)(ws + 33554432);   // alias qkv upper, 8,388,608
    short* WaT = (short*)(ws + 67108864);   // 12,582,912
    short* Qb  = (short*)(ws + 67108864);   // alias WaT (dead after gemm1), 16,777,216
    short* Kb  = (short*)(ws + 83886080);   // 4,194,304
    short* VT  = (short*)(ws + 88080384);   // 4,194,304

    cast_bf16_kernel<<<4096, 256, 0, stream>>>(x, xb, NTOK_ * C_ / 8);
    transcast<<<dim3(32, 48), 256, 0, stream>>>(W_attn, WaT, C_, QKV_);
    gemm_bt<<<dim3(32, 24), 256, 0, stream>>>(xb, WaT, b_attn, qkv, NTOK_, QKV_, C_);
    rope_scatter<<<20480, 256, 0, stream>>>(qkv, fcos, fsin, Qb, Kb);
    v_transpose<<<dim3(32, 2, 8), 256, 0, stream>>>(qkv, VT);
    transcast<<<dim3(32, 32), 256, 0, stream>>>(W_proj, WpT, C_, C_);
    attn_kernel<<<dim3(32, 32), 256, 0, stream>>>(Qb, Kb, VT, y);
    gemm_bt<<<dim3(32, 16), 256, 0, stream>>>(y, WpT, b_proj, out, NTOK_, C_, C_);
}

// Round 5
// 230.537 us; speedup vs baseline: 1.9331x; 1.0602x over previous
//
#include <hip/hip_runtime.h>
#include <hip/hip_bf16.h>
#include <stdint.h>

#define B_ 2
#define T_ 2048
#define C_ 2048
#define NH_ 16
#define NKVH_ 4
#define HS_ 128
#define QKV_ 3072
#define NTOK_ 4096

typedef __attribute__((ext_vector_type(4))) float f32x4;
typedef __attribute__((ext_vector_type(8))) short s16x8;

__device__ __forceinline__ short f2bf(float f) {
    union { float f; unsigned u; } v; v.f = f;
    unsigned r = v.u + 0x7FFFu + ((v.u >> 16) & 1u);
    return (short)(r >> 16);
}

__device__ __forceinline__ void async16(const void* g, void* l) {
    __builtin_amdgcn_global_load_lds(
        (const __attribute__((address_space(1))) void*)g,
        (__attribute__((address_space(3))) void*)l, 16, 0, 0);
}

// ---------------- cast x -> bf16 ----------------
__global__ void cast_bf16_kernel(const float* __restrict__ x, short* __restrict__ out, int n8) {
    int i = blockIdx.x * 256 + threadIdx.x;
    if (i >= n8) return;
    const float4* p = (const float4*)x + (size_t)i * 2;
    float4 a = p[0], b = p[1];
    short o[8] = { f2bf(a.x), f2bf(a.y), f2bf(a.z), f2bf(a.w),
                   f2bf(b.x), f2bf(b.y), f2bf(b.z), f2bf(b.w) };
    *(int4*)(out + (size_t)i * 8) = *(const int4*)o;
}

// ---------------- W [K][N] f32 -> WT [N][K] bf16 ----------------
__global__ void transcast(const float* __restrict__ W, short* __restrict__ WT, int Kd, int Nd) {
    __shared__ float tile[64][65];
    int k0 = blockIdx.x * 64, n0 = blockIdx.y * 64;
    int tid = threadIdx.x;
    int cl = tid & 63, rw = tid >> 6;
    for (int it = 0; it < 16; ++it) {
        int r = it * 4 + rw;
        tile[r][cl] = W[(size_t)(k0 + r) * Nd + n0 + cl];
    }
    __syncthreads();
    for (int it = 0; it < 16; ++it) {
        int n = it * 4 + rw;
        WT[(size_t)(n0 + n) * Kd + k0 + cl] = f2bf(tile[cl][n]);
    }
}

// ---------------- GEMM: A[M][K] bf16 x Bt[N][K] bf16 -> C[M][N] f32 + bias ----------------
__global__ __launch_bounds__(256, 2) void gemm_bt(
    const short* __restrict__ A, const short* __restrict__ Bt,
    const float* __restrict__ bias, float* __restrict__ Cc,
    int M, int N, int K)
{
    __shared__ short As[128 * 64];
    __shared__ short Bs[128 * 64];
    int tid = threadIdx.x;
    int w = tid >> 6, l = tid & 63;
    int lr = l & 15, lg = l >> 4;
    int bm = blockIdx.x, bn = blockIdx.y;
    int wm = (w >> 1) * 64, wn = (w & 1) * 64;
    f32x4 acc[4][4];
#pragma unroll
    for (int i = 0; i < 4; i++)
#pragma unroll
        for (int j = 0; j < 4; j++) { acc[i][j][0]=0.f; acc[i][j][1]=0.f; acc[i][j][2]=0.f; acc[i][j][3]=0.f; }
    int arow = l >> 3, acol = (l & 7) * 8;
    for (int k0 = 0; k0 < K; k0 += 64) {
#pragma unroll
        for (int i = 0; i < 4; i++) {
            int chunk = w * 4 + i;
            int row = chunk * 8 + arow;
            async16(A  + (size_t)(bm * 128 + row) * K + k0 + acol, (char*)As + chunk * 1024);
            async16(Bt + (size_t)(bn * 128 + row) * K + k0 + acol, (char*)Bs + chunk * 1024);
        }
        __syncthreads();
#pragma unroll
        for (int ks = 0; ks < 2; ks++) {
            s16x8 af[4], bf[4];
#pragma unroll
            for (int mi = 0; mi < 4; mi++)
                af[mi] = *(const s16x8*)&As[(wm + mi * 16 + lr) * 64 + ks * 32 + lg * 8];
#pragma unroll
            for (int ni = 0; ni < 4; ni++)
                bf[ni] = *(const s16x8*)&Bs[(wn + ni * 16 + lr) * 64 + ks * 32 + lg * 8];
#pragma unroll
            for (int mi = 0; mi < 4; mi++)
#pragma unroll
                for (int ni = 0; ni < 4; ni++)
                    acc[mi][ni] = __builtin_amdgcn_mfma_f32_16x16x32_bf16(af[mi], bf[ni], acc[mi][ni], 0, 0, 0);
        }
        __syncthreads();
    }
#pragma unroll
    for (int mi = 0; mi < 4; mi++) {
        int row = bm * 128 + wm + mi * 16 + lg * 4;
#pragma unroll
        for (int ni = 0; ni < 4; ni++) {
            int col = bn * 128 + wn + ni * 16 + lr;
            float bv = bias[col];
#pragma unroll
            for (int j = 0; j < 4; j++)
                Cc[(size_t)(row + j) * N + col] = acc[mi][ni][j] + bv;
        }
    }
}

// ---------------- RoPE + scatter to Q [B][NH][T][HS] (pre-scaled by 1/sqrt(HS)), K [B][G][T][HS] bf16 ----------------
__global__ void rope_scatter(const float* __restrict__ qkv,
                             const float* __restrict__ fcos, const float* __restrict__ fsin,
                             short* __restrict__ Q, short* __restrict__ Kb)
{
    const float qscale = 0.08838834764831845f; // 1/sqrt(128), folded into Q
    int idx = blockIdx.x * 256 + threadIdx.x;
    int tok = idx / 1280, p = idx - tok * 1280;
    if (tok >= NTOK_) return;
    int b = tok >> 11, t = tok & 2047;
    if (p < 1024) {
        int h = p >> 6, i = p & 63;
        const float* src = qkv + (size_t)tok * QKV_ + h * 128 + 2 * i;
        float re = src[0], im = src[1];
        float c = fcos[t * 64 + i], s = fsin[t * 64 + i];
        unsigned lo = (unsigned short)f2bf((re * c - im * s) * qscale);
        unsigned hi = (unsigned short)f2bf((re * s + im * c) * qscale);
        *(unsigned*)(Q + ((size_t)(b * NH_ + h) * T_ + t) * HS_ + 2 * i) = lo | (hi << 16);
    } else {
        int pk = p - 1024; int g = pk >> 6, i = pk & 63;
        const float* src = qkv + (size_t)tok * QKV_ + C_ + g * 128 + 2 * i;
        float re = src[0], im = src[1];
        float c = fcos[t * 64 + i], s = fsin[t * 64 + i];
        unsigned lo = (unsigned short)f2bf(re * c - im * s);
        unsigned hi = (unsigned short)f2bf(re * s + im * c);
        *(unsigned*)(Kb + ((size_t)(b * NKVH_ + g) * T_ + t) * HS_ + 2 * i) = lo | (hi << 16);
    }
}

// ---------------- V part of qkv -> VT [B][G][HS][T] bf16 ----------------
__global__ void v_transpose(const float* __restrict__ qkv, short* __restrict__ VT) {
    __shared__ float tile[64][65];
    int t0 = blockIdx.x * 64, d0 = blockIdx.y * 64;
    int bg = blockIdx.z; int b = bg >> 2, g = bg & 3;
    int tid = threadIdx.x; int cl = tid & 63, rw = tid >> 6;
    const float* base = qkv + (size_t)(b * T_ + t0) * QKV_ + C_ + NKVH_ * HS_ + g * HS_ + d0;
    for (int it = 0; it < 16; ++it) {
        int r = it * 4 + rw;
        tile[r][cl] = base[(size_t)r * QKV_ + cl];
    }
    __syncthreads();
    short* out = VT + ((size_t)(b * NKVH_ + g) * HS_ + d0) * T_ + t0;
    for (int it = 0; it < 16; ++it) {
        int d = it * 4 + rw;
        out[(size_t)d * T_ + cl] = f2bf(tile[cl][d]);
    }
}

// ---------------- Flash attention, causal GQA ----------------
// grid: (B*NH=32 fast, T/64=32 q-tiles slow). block: 256 (4 waves x 16 q-rows).
// LPT: qt reversed so the longest blocks (qt=31) dispatch first.
// 2-phase pipeline: double-buffered K/V LDS; stage(st+1) issued BEFORE compute(st);
// single __syncthreads per tile (its implicit vmcnt(0) drains the prefetch).
// launch_bounds(256,2): DO NOT raise — (256,4) forces <=128 unified regs -> spills
// (round 2: VGPR 124->64, FETCH_SIZE 37MB->224MB, dur 174->307us).
// grid.x MUST be 32 (b=bh>>4 assumes B*NH=32; 64 corrupted WpT via OOB Y writes, round 3).
__global__ __launch_bounds__(256, 2) void attn_kernel(
    const short* __restrict__ Qg, const short* __restrict__ Kg,
    const short* __restrict__ VTg, short* __restrict__ Y)
{
    __shared__ short Ks[2][64 * 128];   // [buf][s][d], swizzled, 256B rows
    __shared__ short VTs[2][128 * 64];  // [buf][d][s], swizzled, 128B rows
    __shared__ short Ps[4][16 * 64];    // per-wave P, swizzled, 128B rows
    int tid = threadIdx.x, w = tid >> 6, l = tid & 63;
    int lr = l & 15, lg = l >> 4;
    int qt = 31 - (int)blockIdx.y;   // LPT: longest first
    int bh = blockIdx.x;
    int b = bh >> 4, h = bh & 15, g = h >> 2;
    const short* Qb = Qg + (size_t)(b * NH_ + h) * T_ * HS_;
    const short* Kb = Kg + (size_t)(b * NKVH_ + g) * T_ * HS_;
    const short* Vb = VTg + (size_t)(b * NKVH_ + g) * HS_ * T_;

    auto STAGE = [&](int st, int buf) {
#pragma unroll
        for (int i = 0; i < 4; i++) {
            int chunk = w * 4 + i;
            int poff = chunk * 1024 + l * 16;
            int qoffk = poff ^ (((poff >> 8) & 7) << 4);
            async16(Kb + (size_t)(st * 64 + (qoffk >> 8)) * HS_ + ((qoffk & 255) >> 1),
                    (char*)&Ks[buf][0] + chunk * 1024);
            int qoffv = poff ^ (((poff >> 7) & 7) << 4);
            async16(Vb + (size_t)(qoffv >> 7) * T_ + st * 64 + ((qoffv & 127) >> 1),
                    (char*)&VTs[buf][0] + chunk * 1024);
        }
    };

    s16x8 qf[4];
    int qrow = qt * 64 + w * 16 + lr;
#pragma unroll
    for (int kc = 0; kc < 4; kc++)
        qf[kc] = *(const s16x8*)(Qb + (size_t)qrow * HS_ + kc * 32 + lg * 8);

    f32x4 oacc[8];
#pragma unroll
    for (int i = 0; i < 8; i++) { oacc[i][0]=0.f; oacc[i][1]=0.f; oacc[i][2]=0.f; oacc[i][3]=0.f; }
    float m[4] = {-1e30f, -1e30f, -1e30f, -1e30f};
    float lsum[4] = {0.f, 0.f, 0.f, 0.f};
    int qg0 = qt * 64 + w * 16 + lg * 4;

    STAGE(0, 0);
    __syncthreads();
    int cur = 0;

    for (int st = 0; st <= qt; ++st) {
        if (st < qt) STAGE(st + 1, cur ^ 1);   // prefetch flies under compute
        const char* KsC = (const char*)&Ks[cur][0];
        const char* VsC = (const char*)&VTs[cur][0];

        // S = Q K^T  (Q pre-scaled by 1/sqrt(HS))
        f32x4 sv[4];
#pragma unroll
        for (int ni = 0; ni < 4; ni++) {
            f32x4 a; a[0]=0.f; a[1]=0.f; a[2]=0.f; a[3]=0.f;
#pragma unroll
            for (int kc = 0; kc < 4; kc++) {
                int lo = ((ni * 16 + lr) << 8) + ((kc * 32 + lg * 8) << 1);
                int po = lo ^ (((lo >> 8) & 7) << 4);
                s16x8 kf = *(const s16x8*)(KsC + po);
                a = __builtin_amdgcn_mfma_f32_16x16x32_bf16(qf[kc], kf, a, 0, 0, 0);
            }
            sv[ni] = a;
        }
        // causal mask only on the diagonal tile; row max
        float tmax[4] = {-1e30f, -1e30f, -1e30f, -1e30f};
        if (st == qt) {
#pragma unroll
            for (int ni = 0; ni < 4; ni++) {
                int sg = st * 64 + ni * 16 + lr;
#pragma unroll
                for (int j = 0; j < 4; j++) {
                    float s = sv[ni][j];
                    if (sg > qg0 + j) s = -1e30f;
                    sv[ni][j] = s;
                    tmax[j] = fmaxf(tmax[j], s);
                }
            }
        } else {
#pragma unroll
            for (int ni = 0; ni < 4; ni++)
#pragma unroll
                for (int j = 0; j < 4; j++)
                    tmax[j] = fmaxf(tmax[j], sv[ni][j]);
        }
#pragma unroll
        for (int msk = 1; msk < 16; msk <<= 1)
#pragma unroll
            for (int j = 0; j < 4; j++)
                tmax[j] = fmaxf(tmax[j], __shfl_xor(tmax[j], msk));
        // exact defer-rescale: corr==1 when no row max grew (bit-exact skip)
        bool need = (tmax[0] > m[0]) | (tmax[1] > m[1]) | (tmax[2] > m[2]) | (tmax[3] > m[3]);
        if (__any(need)) {
#pragma unroll
            for (int j = 0; j < 4; j++) {
                float mn = fmaxf(m[j], tmax[j]);
                float corr = __expf(m[j] - mn);
                m[j] = mn;
                lsum[j] *= corr;
#pragma unroll
                for (int dn = 0; dn < 8; dn++) oacc[dn][j] *= corr;
            }
        }
        // P = exp(S - m); per-lane partial row sums (reduced once at epilogue)
#pragma unroll
        for (int ni = 0; ni < 4; ni++)
#pragma unroll
            for (int j = 0; j < 4; j++) {
                float p = __expf(sv[ni][j] - m[j]);
                sv[ni][j] = p;
                lsum[j] += p;
            }
        // P -> wave-private LDS (C-layout -> A-layout bounce), swizzled
#pragma unroll
        for (int ni = 0; ni < 4; ni++)
#pragma unroll
            for (int j = 0; j < 4; j++) {
                int lo = (lg * 4 + j) * 128 + (ni * 16 + lr) * 2;
                int po = lo ^ (((lo >> 7) & 7) << 4);
                *(short*)((char*)&Ps[w][0] + po) = f2bf(sv[ni][j]);
            }
        // O += P V
#pragma unroll
        for (int sc = 0; sc < 2; sc++) {
            int lo = lr * 128 + sc * 64 + lg * 16;
            int po = lo ^ (((lo >> 7) & 7) << 4);
            s16x8 pf = *(const s16x8*)((const char*)&Ps[w][0] + po);
#pragma unroll
            for (int dn = 0; dn < 8; dn++) {
                int lov = (dn * 16 + lr) * 128 + (sc * 32 + lg * 8) * 2;
                int pov = lov ^ (((lov >> 7) & 7) << 4);
                s16x8 vf = *(const s16x8*)(VsC + pov);
                oacc[dn] = __builtin_amdgcn_mfma_f32_16x16x32_bf16(pf, vf, oacc[dn], 0, 0, 0);
            }
        }
        __syncthreads();   // implicit vmcnt(0): prefetch landed; buf[cur] free to overwrite
        cur ^= 1;
    }

    // epilogue: one 16-lane reduction of the deferred row sums
#pragma unroll
    for (int msk = 1; msk < 16; msk <<= 1)
#pragma unroll
        for (int j = 0; j < 4; j++)
            lsum[j] += __shfl_xor(lsum[j], msk);
    float inv[4];
#pragma unroll
    for (int j = 0; j < 4; j++) inv[j] = 1.0f / lsum[j];
#pragma unroll
    for (int dn = 0; dn < 8; dn++)
#pragma unroll
        for (int j = 0; j < 4; j++) {
            int trow = qt * 64 + w * 16 + lg * 4 + j;
            Y[(size_t)(b * T_ + trow) * C_ + h * 128 + dn * 16 + lr] = f2bf(oacc[dn][j] * inv[j]);
        }
}

extern "C" void kernel_launch(void* const* d_in, const int* in_sizes, int n_in,
                              void* d_out, int out_size, void* d_ws, size_t ws_size,
                              hipStream_t stream)
{
    const float* x      = (const float*)d_in[0];
    const float* fcos   = (const float*)d_in[1];
    const float* fsin   = (const float*)d_in[2];
    const float* W_attn = (const float*)d_in[3];
    const float* b_attn = (const float*)d_in[4];
    const float* W_proj = (const float*)d_in[5];
    const float* b_proj = (const float*)d_in[6];
    float* out = (float*)d_out;
    char* ws = (char*)d_ws;

    // workspace layout (92.3 MB, with dead-buffer aliasing)
    short* xb  = (short*)(ws + 0);          // 16,777,216
    float* qkv = (float*)(ws + 16777216);   // 50,331,648  [16777216 .. 67108864)
    short* y   = (short*)(ws + 16777216);   // alias qkv lower (qkv dead by then)
    short* WpT = (short*)(ws + 33554432);   // alias qkv upper, 8,388,608
    short* WaT = (short*)(ws + 67108864);   // 12,582,912
    short* Qb  = (short*)(ws + 67108864);   // alias WaT (dead after gemm1), 16,777,216
    short* Kb  = (short*)(ws + 83886080);   // 4,194,304
    short* VT  = (short*)(ws + 88080384);   // 4,194,304

    cast_bf16_kernel<<<4096, 256, 0, stream>>>(x, xb, NTOK_ * C_ / 8);
    transcast<<<dim3(32, 48), 256, 0, stream>>>(W_attn, WaT, C_, QKV_);
    gemm_bt<<<dim3(32, 24), 256, 0, stream>>>(xb, WaT, b_attn, qkv, NTOK_, QKV_, C_);
    rope_scatter<<<20480, 256, 0, stream>>>(qkv, fcos, fsin, Qb, Kb);
    v_transpose<<<dim3(32, 2, 8), 256, 0, stream>>>(qkv, VT);
    transcast<<<dim3(32, 32), 256, 0, stream>>>(W_proj, WpT, C_, C_);
    attn_kernel<<<dim3(32, 32), 256, 0, stream>>>(Qb, Kb, VT, y);
    gemm_bt<<<dim3(32, 16), 256, 0, stream>>>(y, WpT, b_proj, out, NTOK_, C_, C_);
}

// Round 7
// 225.289 us; speedup vs baseline: 1.9781x; 1.0233x over previous
//
#include <hip/hip_runtime.h>
#include <hip/hip_bf16.h>
#include <stdint.h>

#define B_ 2
#define T_ 2048
#define C_ 2048
#define NH_ 16
#define NKVH_ 4
#define HS_ 128
#define QKV_ 3072
#define NTOK_ 4096

typedef __attribute__((ext_vector_type(4))) float f32x4;
typedef __attribute__((ext_vector_type(16))) float f32x16;
typedef __attribute__((ext_vector_type(8))) short s16x8;

__device__ __forceinline__ short f2bf(float f) {
    union { float f; unsigned u; } v; v.f = f;
    unsigned r = v.u + 0x7FFFu + ((v.u >> 16) & 1u);
    return (short)(r >> 16);
}

__device__ __forceinline__ void async16(const void* g, void* l) {
    __builtin_amdgcn_global_load_lds(
        (const __attribute__((address_space(1))) void*)g,
        (__attribute__((address_space(3))) void*)l, 16, 0, 0);
}

// ---------------- cast x -> bf16 ----------------
__global__ void cast_bf16_kernel(const float* __restrict__ x, short* __restrict__ out, int n8) {
    int i = blockIdx.x * 256 + threadIdx.x;
    if (i >= n8) return;
    const float4* p = (const float4*)x + (size_t)i * 2;
    float4 a = p[0], b = p[1];
    short o[8] = { f2bf(a.x), f2bf(a.y), f2bf(a.z), f2bf(a.w),
                   f2bf(b.x), f2bf(b.y), f2bf(b.z), f2bf(b.w) };
    *(int4*)(out + (size_t)i * 8) = *(const int4*)o;
}

// ---------------- W [K][N] f32 -> WT [N][K] bf16 ----------------
__global__ void transcast(const float* __restrict__ W, short* __restrict__ WT, int Kd, int Nd) {
    __shared__ float tile[64][65];
    int k0 = blockIdx.x * 64, n0 = blockIdx.y * 64;
    int tid = threadIdx.x;
    int cl = tid & 63, rw = tid >> 6;
    for (int it = 0; it < 16; ++it) {
        int r = it * 4 + rw;
        tile[r][cl] = W[(size_t)(k0 + r) * Nd + n0 + cl];
    }
    __syncthreads();
    for (int it = 0; it < 16; ++it) {
        int n = it * 4 + rw;
        WT[(size_t)(n0 + n) * Kd + k0 + cl] = f2bf(tile[cl][n]);
    }
}

// ---------------- GEMM: A[M][K] bf16 x Bt[N][K] bf16 -> C[M][N] f32 + bias ----------------
__global__ __launch_bounds__(256, 2) void gemm_bt(
    const short* __restrict__ A, const short* __restrict__ Bt,
    const float* __restrict__ bias, float* __restrict__ Cc,
    int M, int N, int K)
{
    __shared__ short As[128 * 64];
    __shared__ short Bs[128 * 64];
    int tid = threadIdx.x;
    int w = tid >> 6, l = tid & 63;
    int lr = l & 15, lg = l >> 4;
    int bm = blockIdx.x, bn = blockIdx.y;
    int wm = (w >> 1) * 64, wn = (w & 1) * 64;
    f32x4 acc[4][4];
#pragma unroll
    for (int i = 0; i < 4; i++)
#pragma unroll
        for (int j = 0; j < 4; j++) { acc[i][j][0]=0.f; acc[i][j][1]=0.f; acc[i][j][2]=0.f; acc[i][j][3]=0.f; }
    int arow = l >> 3, acol = (l & 7) * 8;
    for (int k0 = 0; k0 < K; k0 += 64) {
#pragma unroll
        for (int i = 0; i < 4; i++) {
            int chunk = w * 4 + i;
            int row = chunk * 8 + arow;
            async16(A  + (size_t)(bm * 128 + row) * K + k0 + acol, (char*)As + chunk * 1024);
            async16(Bt + (size_t)(bn * 128 + row) * K + k0 + acol, (char*)Bs + chunk * 1024);
        }
        __syncthreads();
#pragma unroll
        for (int ks = 0; ks < 2; ks++) {
            s16x8 af[4], bf[4];
#pragma unroll
            for (int mi = 0; mi < 4; mi++)
                af[mi] = *(const s16x8*)&As[(wm + mi * 16 + lr) * 64 + ks * 32 + lg * 8];
#pragma unroll
            for (int ni = 0; ni < 4; ni++)
                bf[ni] = *(const s16x8*)&Bs[(wn + ni * 16 + lr) * 64 + ks * 32 + lg * 8];
#pragma unroll
            for (int mi = 0; mi < 4; mi++)
#pragma unroll
                for (int ni = 0; ni < 4; ni++)
                    acc[mi][ni] = __builtin_amdgcn_mfma_f32_16x16x32_bf16(af[mi], bf[ni], acc[mi][ni], 0, 0, 0);
        }
        __syncthreads();
    }
#pragma unroll
    for (int mi = 0; mi < 4; mi++) {
        int row = bm * 128 + wm + mi * 16 + lg * 4;
#pragma unroll
        for (int ni = 0; ni < 4; ni++) {
            int col = bn * 128 + wn + ni * 16 + lr;
            float bv = bias[col];
#pragma unroll
            for (int j = 0; j < 4; j++)
                Cc[(size_t)(row + j) * N + col] = acc[mi][ni][j] + bv;
        }
    }
}

// ---------------- RoPE + scatter to Q [B][NH][T][HS] (pre-scaled by 1/sqrt(HS)), K [B][G][T][HS] bf16 ----------------
__global__ void rope_scatter(const float* __restrict__ qkv,
                             const float* __restrict__ fcos, const float* __restrict__ fsin,
                             short* __restrict__ Q, short* __restrict__ Kb)
{
    const float qscale = 0.08838834764831845f; // 1/sqrt(128), folded into Q
    int idx = blockIdx.x * 256 + threadIdx.x;
    int tok = idx / 1280, p = idx - tok * 1280;
    if (tok >= NTOK_) return;
    int b = tok >> 11, t = tok & 2047;
    if (p < 1024) {
        int h = p >> 6, i = p & 63;
        const float* src = qkv + (size_t)tok * QKV_ + h * 128 + 2 * i;
        float re = src[0], im = src[1];
        float c = fcos[t * 64 + i], s = fsin[t * 64 + i];
        unsigned lo = (unsigned short)f2bf((re * c - im * s) * qscale);
        unsigned hi = (unsigned short)f2bf((re * s + im * c) * qscale);
        *(unsigned*)(Q + ((size_t)(b * NH_ + h) * T_ + t) * HS_ + 2 * i) = lo | (hi << 16);
    } else {
        int pk = p - 1024; int g = pk >> 6, i = pk & 63;
        const float* src = qkv + (size_t)tok * QKV_ + C_ + g * 128 + 2 * i;
        float re = src[0], im = src[1];
        float c = fcos[t * 64 + i], s = fsin[t * 64 + i];
        unsigned lo = (unsigned short)f2bf(re * c - im * s);
        unsigned hi = (unsigned short)f2bf(re * s + im * c);
        *(unsigned*)(Kb + ((size_t)(b * NKVH_ + g) * T_ + t) * HS_ + 2 * i) = lo | (hi << 16);
    }
}

// ---------------- V part of qkv -> VT [B][G][HS][T] bf16 ----------------
__global__ void v_transpose(const float* __restrict__ qkv, short* __restrict__ VT) {
    __shared__ float tile[64][65];
    int t0 = blockIdx.x * 64, d0 = blockIdx.y * 64;
    int bg = blockIdx.z; int b = bg >> 2, g = bg & 3;
    int tid = threadIdx.x; int cl = tid & 63, rw = tid >> 6;
    const float* base = qkv + (size_t)(b * T_ + t0) * QKV_ + C_ + NKVH_ * HS_ + g * HS_ + d0;
    for (int it = 0; it < 16; ++it) {
        int r = it * 4 + rw;
        tile[r][cl] = base[(size_t)r * QKV_ + cl];
    }
    __syncthreads();
    short* out = VT + ((size_t)(b * NKVH_ + g) * HS_ + d0) * T_ + t0;
    for (int it = 0; it < 16; ++it) {
        int d = it * 4 + rw;
        out[(size_t)d * T_ + cl] = f2bf(tile[cl][d]);
    }
}

// ---------------- Flash attention, causal GQA — swapped-QK^T 32x32, LDS P-bounce ----------------
// grid: (B*NH=32 fast, T/128=16 q-tiles slow, LPT-reversed). block: 256 (4 waves x 32 q-rows).
// S^T = mfma32x32x16(A=K, B=Q): lane q=l&31 holds 32 s-values of ONE q-row -> per-lane
// scalar softmax state; 1 shfl_xor(32) merges the q-row's two half-lanes.
// P goes through wave-private swizzled LDS (round-5-PROVEN write-scalar/read-vector bounce).
// O^T = mfma32x32x16(A=V^T, B=P): q stays lane-local.
// 2-phase dbuf loop (prefetch st+1 before compute st, 1 barrier/tile).
// launch_bounds(256,2): (256,4) spills (round 2). grid.x MUST be 32 (b=bh>>4, round 3).
__global__ __launch_bounds__(256, 2) void attn_kernel(
    const short* __restrict__ Qg, const short* __restrict__ Kg,
    const short* __restrict__ VTg, short* __restrict__ Y)
{
    __shared__ short Ks[2][64 * 128];   // [buf][s][d], swizzled (256B rows, XOR (row&7)<<4)
    __shared__ short VTs[2][128 * 64];  // [buf][d][s], swizzled (128B rows, XOR (row&7)<<4)
    __shared__ short Ps[4][32 * 64];    // per-wave P: [q 32][s 64], swizzled 128B rows
    int tid = threadIdx.x, w = tid >> 6, l = tid & 63;
    int l31 = l & 31, hi = l >> 5;
    int qt = 15 - (int)blockIdx.y;   // LPT: longest first
    int bh = blockIdx.x;
    int b = bh >> 4, h = bh & 15, g = h >> 2;
    const short* Qb = Qg + (size_t)(b * NH_ + h) * T_ * HS_;
    const short* Kb = Kg + (size_t)(b * NKVH_ + g) * T_ * HS_;
    const short* Vb = VTg + (size_t)(b * NKVH_ + g) * HS_ * T_;

    auto STAGE = [&](int st, int buf) {
#pragma unroll
        for (int i = 0; i < 4; i++) {
            int chunk = w * 4 + i;
            int poff = chunk * 1024 + l * 16;
            int qoffk = poff ^ (((poff >> 8) & 7) << 4);
            async16(Kb + (size_t)(st * 64 + (qoffk >> 8)) * HS_ + ((qoffk & 255) >> 1),
                    (char*)&Ks[buf][0] + chunk * 1024);
            int qoffv = poff ^ (((poff >> 7) & 7) << 4);
            async16(Vb + (size_t)(qoffv >> 7) * T_ + st * 64 + ((qoffv & 127) >> 1),
                    (char*)&VTs[buf][0] + chunk * 1024);
        }
    };

    int qw = qt * 128 + w * 32;      // wave's first q-row
    int qglob = qw + l31;            // this lane's q-row

    // Q fragment (B-operand): lane holds Q[qglob][d = dc*16 + hi*8 + i]
    s16x8 qf[8];
#pragma unroll
    for (int dc = 0; dc < 8; dc++)
        qf[dc] = *(const s16x8*)(Qb + (size_t)qglob * HS_ + dc * 16 + hi * 8);

    // O^T accumulators: oacc[db][r] = O[d = db*32 + (r&3)+8*(r>>2)+4*hi][qglob]
    f32x16 oacc[4];
#pragma unroll
    for (int db = 0; db < 4; db++)
#pragma unroll
        for (int i = 0; i < 16; i++) oacc[db][i] = 0.f;
    float m = -1e30f, lsum = 0.f;
    int nst = 2 * qt + 2;

    STAGE(0, 0);
    __syncthreads();
    int cur = 0;

    for (int st = 0; st < nst; ++st) {
        if (st + 1 < nst) STAGE(st + 1, cur ^ 1);   // prefetch flies under compute
        if (st * 64 <= qw) {                        // skip fully-masked tiles (wave-uniform)
            const char* KsC = (const char*)&Ks[cur][0];
            const char* VsC = (const char*)&VTs[cur][0];
            char* PsC = (char*)&Ps[w][0];

            // S^T[s][q] = sum_d K[s][d] * Q[q][d]  (Q pre-scaled by 1/sqrt(HS))
            f32x16 sacc[2];
#pragma unroll
            for (int sb = 0; sb < 2; sb++) {
                f32x16 a;
#pragma unroll
                for (int i = 0; i < 16; i++) a[i] = 0.f;
#pragma unroll
                for (int dc = 0; dc < 8; dc++) {
                    int lo = (sb * 32 + l31) * 256 + dc * 32 + hi * 16;
                    int po = lo ^ (((lo >> 8) & 7) << 4);
                    s16x8 kf = *(const s16x8*)(KsC + po);
                    a = __builtin_amdgcn_mfma_f32_32x32x16_bf16(kf, qf[dc], a, 0, 0, 0);
                }
                sacc[sb] = a;
            }
            // causal mask (boundary tiles only); lane's s-rows: sb*32 + (r&3)+8*(r>>2)+4*hi
            if (st * 64 + 63 > qw) {
#pragma unroll
                for (int sb = 0; sb < 2; sb++)
#pragma unroll
                    for (int r = 0; r < 16; r++) {
                        int s = st * 64 + sb * 32 + (r & 3) + 8 * (r >> 2) + 4 * hi;
                        if (s > qglob) sacc[sb][r] = -1e30f;
                    }
            }
            // row max: local fmax + 1 cross-half merge
            float tm = -1e30f;
#pragma unroll
            for (int sb = 0; sb < 2; sb++)
#pragma unroll
                for (int r = 0; r < 16; r++) tm = fmaxf(tm, sacc[sb][r]);
            tm = fmaxf(tm, __shfl_xor(tm, 32));
            // exact defer-rescale
            if (__any(tm > m)) {
                float mn = fmaxf(m, tm);
                float corr = __expf(m - mn);
                m = mn; lsum *= corr;
#pragma unroll
                for (int db = 0; db < 4; db++)
#pragma unroll
                    for (int r = 0; r < 16; r++) oacc[db][r] *= corr;
            }
            // P = exp(S^T - m) -> wave-private LDS [q=l31][s], swizzled (round-5 pattern)
#pragma unroll
            for (int sb = 0; sb < 2; sb++)
#pragma unroll
                for (int r = 0; r < 16; r++) {
                    float p = __expf(sacc[sb][r] - m);
                    lsum += p;
                    int sl = sb * 32 + (r & 3) + 8 * (r >> 2) + 4 * hi;
                    int lo = l31 * 128 + sl * 2;
                    int po = lo ^ (((lo >> 7) & 7) << 4);
                    *(short*)(PsC + po) = f2bf(p);
                }
            // O^T += V^T · P  (A = V^T d-rows from LDS, B = P from LDS bounce)
#pragma unroll
            for (int sc = 0; sc < 4; sc++) {
                int lp = l31 * 128 + sc * 32 + hi * 16;
                int pp = lp ^ (((lp >> 7) & 7) << 4);
                s16x8 pf = *(const s16x8*)(PsC + pp);
#pragma unroll
                for (int db = 0; db < 4; db++) {
                    int lo = (db * 32 + l31) * 128 + sc * 32 + hi * 16;
                    int po = lo ^ (((lo >> 7) & 7) << 4);
                    s16x8 vf = *(const s16x8*)(VsC + po);
                    oacc[db] = __builtin_amdgcn_mfma_f32_32x32x16_bf16(vf, pf, oacc[db], 0, 0, 0);
                }
            }
        }
        __syncthreads();   // implicit vmcnt(0): prefetch landed; buf[cur] free
        cur ^= 1;
    }

    // epilogue: merge half-row sums, normalize, write O (pairs of consecutive d)
    lsum += __shfl_xor(lsum, 32);
    float inv = 1.0f / lsum;
    short* Yrow = Y + (size_t)(b * T_ + qglob) * C_ + h * 128;
#pragma unroll
    for (int db = 0; db < 4; db++)
#pragma unroll
        for (int pr = 0; pr < 8; pr++) {
            unsigned u0 = (unsigned short)f2bf(oacc[db][2 * pr] * inv);
            unsigned u1 = (unsigned short)f2bf(oacc[db][2 * pr + 1] * inv);
            int d = db * 32 + ((2 * pr) & 3) + 8 * (pr >> 1) + 4 * hi;
            *(unsigned*)(Yrow + d) = u0 | (u1 << 16);
        }
}

extern "C" void kernel_launch(void* const* d_in, const int* in_sizes, int n_in,
                              void* d_out, int out_size, void* d_ws, size_t ws_size,
                              hipStream_t stream)
{
    const float* x      = (const float*)d_in[0];
    const float* fcos   = (const float*)d_in[1];
    const float* fsin   = (const float*)d_in[2];
    const float* W_attn = (const float*)d_in[3];
    const float* b_attn = (const float*)d_in[4];
    const float* W_proj = (const float*)d_in[5];
    const float* b_proj = (const float*)d_in[6];
    float* out = (float*)d_out;
    char* ws = (char*)d_ws;

    // workspace layout (92.3 MB, with dead-buffer aliasing)
    short* xb  = (short*)(ws + 0);          // 16,777,216
    float* qkv = (float*)(ws + 16777216);   // 50,331,648  [16777216 .. 67108864)
    short* y   = (short*)(ws + 16777216);   // alias qkv lower (qkv dead by then)
    short* WpT = (short*)(ws + 33554432);   // alias qkv upper, 8,388,608
    short* WaT = (short*)(ws + 67108864);   // 12,582,912
    short* Qb  = (short*)(ws + 67108864);   // alias WaT (dead after gemm1), 16,777,216
    short* Kb  = (short*)(ws + 83886080);   // 4,194,304
    short* VT  = (short*)(ws + 88080384);   // 4,194,304

    cast_bf16_kernel<<<4096, 256, 0, stream>>>(x, xb, NTOK_ * C_ / 8);
    transcast<<<dim3(32, 48), 256, 0, stream>>>(W_attn, WaT, C_, QKV_);
    gemm_bt<<<dim3(32, 24), 256, 0, stream>>>(xb, WaT, b_attn, qkv, NTOK_, QKV_, C_);
    rope_scatter<<<20480, 256, 0, stream>>>(qkv, fcos, fsin, Qb, Kb);
    v_transpose<<<dim3(32, 2, 8), 256, 0, stream>>>(qkv, VT);
    transcast<<<dim3(32, 32), 256, 0, stream>>>(W_proj, WpT, C_, C_);
    attn_kernel<<<dim3(32, 16), 256, 0, stream>>>(Qb, Kb, VT, y);
    gemm_bt<<<dim3(32, 16), 256, 0, stream>>>(y, WpT, b_proj, out, NTOK_, C_, C_);
}